// Round 2
// baseline (510.935 us; speedup 1.0000x reference)
//
#include <hip/hip_runtime.h>
#include <hip/hip_bf16.h>
#include <math.h>

typedef __attribute__((ext_vector_type(8))) short bf16x8;
typedef __attribute__((ext_vector_type(4))) float f32x4;

#define B_ 8192
#define F_ 26
#define D_ 32
#define V_ 100000

// ---- ws layout (bytes), 16B-aligned ----
static const size_t OFF_VB   = 0;             // bf16 8192x832  = 13631488
static const size_t OFF_FD0  = 13631488;      // f32 8192       = 32768  (lin+cin dot)
static const size_t OFF_H1B  = 13664256;      // bf16 8192x400  = 6553600
static const size_t OFF_W1T  = 20217856;      // bf16 400x832   = 665600
static const size_t OFF_W2T  = 20883456;      // bf16 400x400   = 320000
static const size_t OFF_K2T  = 21203456;      // bf16 2x352x32  = 45056  (hi plane, lo plane)
// total ~21.25 MB

// RNE bf16 (weights, one-time)
static __device__ __forceinline__ unsigned short f2b(float f) {
    unsigned int u = __float_as_uint(f);
    return (unsigned short)((u + 0x7FFF + ((u >> 16) & 1)) >> 16);
}
// truncating bf16 (activations)
static __device__ __forceinline__ unsigned short f2bt(float f) {
    return (unsigned short)(__float_as_uint(f) >> 16);
}
// pack two truncated bf16 in one v_perm_b32
static __device__ __forceinline__ unsigned int pk2t(float a, float b) {
    return __builtin_amdgcn_perm(__float_as_uint(b), __float_as_uint(a), 0x07060302u);
}
static __device__ __forceinline__ float bf2f(unsigned short u) {
    return __uint_as_float(((unsigned int)u) << 16);
}

// ======== K0: W1/W2 transposes + K2T direct (M folded in, no intermediate) ========
static __device__ __forceinline__ void transpose_body(
    const float* __restrict__ src, unsigned short* __restrict__ dst,
    int K, int N, int bx, int by)
{
    __shared__ float tl[32][33];
    const int lx = threadIdx.x & 31, ly = threadIdx.x >> 5;
    const int n0 = bx * 32, k0 = by * 32;
#pragma unroll
    for (int i = 0; i < 4; ++i) {
        int k = k0 + ly + i * 8, n = n0 + lx;
        if (k < K && n < N) tl[ly + i * 8][lx] = src[(size_t)k * N + n];
    }
    __syncthreads();
#pragma unroll
    for (int i = 0; i < 4; ++i) {
        int n = n0 + ly + i * 8, k = k0 + lx;
        if (k < K && n < N) dst[(size_t)n * K + k] = f2b(tl[lx][ly + i * 8]);
    }
}

__global__ __launch_bounds__(256) void k0_all(
    const float* __restrict__ W1, const float* __restrict__ W2,
    const float* __restrict__ W0, const float* __restrict__ Wc1,
    const float* __restrict__ wout,
    unsigned short* __restrict__ W1t, unsigned short* __restrict__ W2t,
    unsigned short* __restrict__ K2T)
{
    __shared__ float Mi[128];
    int bid = blockIdx.x;
    const int t = threadIdx.x;
    if (bid < 338) { transpose_body(W1, W1t, 832, 400, bid % 13, bid / 13); return; }
    bid -= 338;
    if (bid < 169) { transpose_body(W2, W2t, 400, 400, bid % 13, bid / 13); return; }
    bid -= 169;
    // K2 block: fixed i = bid (0..31). Mi[j] = sum_h Wc1[i][j][h]*wout2[h] (i<26),
    // i==26 -> wout1[j], i>26 -> 0. Then K2T[q][i] = sum_j W0sym[q,j]*Mi[j], hi/lo bf16.
    const int i = bid;
    if (t < 128) {
        float m = 0.f;
        if (i < F_) {
            const float* row = Wc1 + ((size_t)i * 128 + t) * 128;
            for (int h = 0; h < 128; h += 4) {
                float4 a = *(const float4*)(row + h);
                m = fmaf(a.x, wout[129 + h],     m);
                m = fmaf(a.y, wout[129 + h + 1], m);
                m = fmaf(a.z, wout[129 + h + 2], m);
                m = fmaf(a.w, wout[129 + h + 3], m);
            }
        } else if (i == F_) {
            m = wout[1 + t];
        }
        Mi[t] = m;
    }
    __syncthreads();
    for (int q = t; q < 352; q += 256) {
        float s = 0.f;
        if (q < 351 && i <= F_) {
            int a = 0, base = 0;
            while (base + (F_ - a) <= q) { base += F_ - a; ++a; }
            int b = a + (q - base);
            const float* r0 = W0 + ((size_t)a * F_ + b) * 128;
            const float* r1 = W0 + ((size_t)b * F_ + a) * 128;
            if (a == b) {
                for (int j = 0; j < 128; j += 4) {
                    float4 w = *(const float4*)(r0 + j);
                    s += w.x * Mi[j] + w.y * Mi[j + 1] + w.z * Mi[j + 2] + w.w * Mi[j + 3];
                }
            } else {
                for (int j = 0; j < 128; j += 4) {
                    float4 w  = *(const float4*)(r0 + j);
                    float4 w1 = *(const float4*)(r1 + j);
                    s += (w.x + w1.x) * Mi[j]     + (w.y + w1.y) * Mi[j + 1]
                       + (w.z + w1.z) * Mi[j + 2] + (w.w + w1.w) * Mi[j + 3];
                }
            }
        }
        unsigned short hi = f2b(s);
        float lo = s - bf2f(hi);
        K2T[q * 32 + i] = hi;                 // hi plane [352][32]
        K2T[11264 + q * 32 + i] = f2b(lo);    // lo plane
    }
}

// ======== K1: one b per block: gather + Ht MFMA + in-register pe dot ========
__global__ __launch_bounds__(256) void k1_embed_cin(
    const int*   __restrict__ sparse,
    const float* __restrict__ E,
    const unsigned short* __restrict__ K2T,
    const float* __restrict__ wlin,
    const float* __restrict__ blin,
    const float* __restrict__ wout,
    unsigned short* __restrict__ vb,
    float* __restrict__ fdot0)
{
    __shared__ __align__(16) unsigned short embT[32][40];  // [d][i]; col26=1.0, 27..31=0
    __shared__ unsigned int PQ[352];                        // i | (j<<16)
    __shared__ int idxs[F_];
    __shared__ float red[4];

    const int b = blockIdx.x, t = threadIdx.x;
    float cind = 0.f;

    if (t < F_) {
        int id = sparse[b * F_ + t];
        idxs[t] = id;
        cind = (float)id * wlin[t] * wout[0];          // lin folded into the block dot
        int base = F_ * t - (t * (t - 1)) / 2;
        for (int j = t; j < F_; ++j)
            PQ[base + j - t] = (unsigned)t | ((unsigned)j << 16);
    }
    if (t == F_) PQ[351] = 0u;                          // pad row (K2T row 351 is zero)
    if (t >= 32 && t < 64) {                            // ones col + zero pad cols
        int d = t - 32;
        embT[d][26] = 0x3F80;                           // bf16 1.0
        embT[d][27] = 0; embT[d][28] = 0; embT[d][29] = 0;
        embT[d][30] = 0; embT[d][31] = 0;
    }
    __syncthreads();

    // gather 26 rows x 8 float4 -> vb (global, bf16) + embT (transposed LDS)
    if (t < 208) {
        int f = t >> 3, q = t & 7;
        float4 v4 = *(const float4*)(E + ((size_t)f * V_ + idxs[f]) * D_ + q * 4);
        uint2 uu; uu.x = pk2t(v4.x, v4.y); uu.y = pk2t(v4.z, v4.w);
        *(uint2*)(vb + (size_t)b * 832 + f * 32 + q * 4) = uu;
        embT[q * 4 + 0][f] = f2bt(v4.x);
        embT[q * 4 + 1][f] = f2bt(v4.y);
        embT[q * 4 + 2][f] = f2bt(v4.z);
        embT[q * 4 + 3][f] = f2bt(v4.w);
    }
    __syncthreads();

    // Ht[d][q] = sum_i embT[d][i]*K2[q][i] via MFMA; dot vs pe[q,d]=emb_i[d]*emb_j[d]
    const int wave = t >> 6, lane = t & 63;
    const int lr = lane & 15, lg = lane >> 4;
    const int mt = wave & 1;            // m-tile (d-half) fixed per wave
    const int nb = wave >> 1;           // nt = 2*s + nb
    bf16x8 af = *(const bf16x8*)&embT[mt * 16 + lr][lg * 8];
    const unsigned short* ebase = &embT[mt * 16 + lg * 4][0];
    const unsigned short* Kb = K2T + (size_t)lr * 32 + lg * 8;

#pragma unroll
    for (int s = 0; s < 11; ++s) {
        const int nt = 2 * s + nb;
        bf16x8 bh = *(const bf16x8*)(Kb + (size_t)nt * 512);
        bf16x8 bl = *(const bf16x8*)(Kb + 11264 + (size_t)nt * 512);
        f32x4 h = {};
        h = __builtin_amdgcn_mfma_f32_16x16x32_bf16(af, bl, h, 0, 0, 0);
        h = __builtin_amdgcn_mfma_f32_16x16x32_bf16(af, bh, h, 0, 0, 0);
        unsigned pq = PQ[nt * 16 + lr];
        int oi = (int)(pq & 0xFFFFu), oj = (int)(pq >> 16);
#pragma unroll
        for (int r = 0; r < 4; ++r) {
            float ei = bf2f(ebase[r * 40 + oi]);
            float ej = bf2f(ebase[r * 40 + oj]);
            cind = fmaf(ei * ej, h[r], cind);
        }
    }

#pragma unroll
    for (int off = 1; off <= 32; off <<= 1) cind += __shfl_xor(cind, off, 64);
    if (lane == 0) red[wave] = cind;
    __syncthreads();
    if (t == 0) fdot0[b] = red[0] + red[1] + red[2] + red[3] + blin[0] * wout[0];
}

// ======== GEMM core: 64x128 tile, BK=32, reg prefetch (used by k2_h1) ========
static __device__ __forceinline__ void gemm_core(
    const unsigned short* __restrict__ A, int lda,
    const unsigned short* __restrict__ Bt, int ldb, int N,
    int m0, int n0, int kbase, int kend,
    unsigned short (*As)[40], unsigned short (*Bs)[40],
    f32x4 (*acc)[2])
{
    const int t = threadIdx.x;
    const int wave = t >> 6, lane = t & 63;
    const int lr = lane & 15, lg = lane >> 4;
    const int wn = wave * 32;
    const int ar = t >> 2, kg = (t & 3) * 8;

    const unsigned short* aptr = A  + (size_t)(m0 + ar) * lda + kbase + kg;
    const unsigned short* bp0  = Bt + (size_t)(n0 + ar) * ldb + kbase + kg;
    const unsigned short* bp1  = Bt + (size_t)(n0 + 64 + ar) * ldb + kbase + kg;
    const bool bn0 = (n0 + ar) < N, bn1 = (n0 + 64 + ar) < N;
    const uint4 z4 = make_uint4(0u, 0u, 0u, 0u);
    const int nkt = (kend - kbase + 31) >> 5;
    uint4 av, bv0, bv1;
    {
        int k = kbase + kg;
        av  = (k < kend)        ? *(const uint4*)aptr : z4;
        bv0 = (bn0 && k < kend) ? *(const uint4*)bp0  : z4;
        bv1 = (bn1 && k < kend) ? *(const uint4*)bp1  : z4;
    }
    for (int kt = 0; kt < nkt; ++kt) {
        *(uint4*)&As[ar][kg]      = av;
        *(uint4*)&Bs[ar][kg]      = bv0;
        *(uint4*)&Bs[64 + ar][kg] = bv1;
        __syncthreads();
        if (kt + 1 < nkt) {
            int kn = kbase + (kt + 1) * 32 + kg;
            av  = (kn < kend)        ? *(const uint4*)(aptr + (kt + 1) * 32) : z4;
            bv0 = (bn0 && kn < kend) ? *(const uint4*)(bp0  + (kt + 1) * 32) : z4;
            bv1 = (bn1 && kn < kend) ? *(const uint4*)(bp1  + (kt + 1) * 32) : z4;
        }
        bf16x8 af[4], bfr[2];
#pragma unroll
        for (int i = 0; i < 4; ++i) af[i]  = *(const bf16x8*)&As[i * 16 + lr][lg * 8];
#pragma unroll
        for (int j = 0; j < 2; ++j) bfr[j] = *(const bf16x8*)&Bs[wn + j * 16 + lr][lg * 8];
#pragma unroll
        for (int i = 0; i < 4; ++i)
#pragma unroll
            for (int j = 0; j < 2; ++j)
                acc[i][j] = __builtin_amdgcn_mfma_f32_16x16x32_bf16(af[i], bfr[j], acc[i][j], 0, 0, 0);
        __syncthreads();
    }
}

// K2a: h1 = relu(vb@W1+b1) (bf16 out)
__global__ __launch_bounds__(256) void k2_h1(
    const unsigned short* __restrict__ vb, const unsigned short* __restrict__ W1t,
    const float* __restrict__ b1, unsigned short* __restrict__ h1b)
{
    __shared__ __align__(16) unsigned short As[64][40];
    __shared__ __align__(16) unsigned short Bs[128][40];
    const int t = threadIdx.x;
    const int wave = t >> 6, lane = t & 63;
    const int lr = lane & 15, lg = lane >> 4;
    const int m0 = blockIdx.y * 64, n0 = blockIdx.x * 128;
    f32x4 acc[4][2] = {};
    gemm_core(vb, 832, W1t, 832, 400, m0, n0, 0, 832, As, Bs, acc);
#pragma unroll
    for (int i = 0; i < 4; ++i) {
        int mrow = m0 + i * 16 + lg * 4;
#pragma unroll
        for (int j = 0; j < 2; ++j) {
            int col = n0 + wave * 32 + j * 16 + lr;
            if (col >= 400) continue;
            float bb = b1[col];
#pragma unroll
            for (int r = 0; r < 4; ++r)
                h1b[(size_t)(mrow + r) * 400 + col] = f2bt(fmaxf(acc[i][j][r] + bb, 0.f));
        }
    }
}

// K2b fused: h2 dot + final sigmoid. One block = 32 rows, full N sweep, B from L2.
__global__ __launch_bounds__(256) void k2_h2f(
    const unsigned short* __restrict__ h1b, const unsigned short* __restrict__ W2t,
    const float* __restrict__ b2, const float* __restrict__ wout,
    const float* __restrict__ fdot0, const float* __restrict__ dense,
    const float* __restrict__ bout, float* __restrict__ out)
{
    __shared__ __align__(16) unsigned short As[32][424];   // rows 0..31, cols 0..399 + zero pad
    __shared__ float red[4][32];
    const int t = threadIdx.x;
    const int m0 = blockIdx.x * 32;

    // load h1 rows (32 x 400 bf16, uint4 vectorized), zero pad cols 400..423
    for (int idx = t; idx < 1600; idx += 256) {
        int row = idx / 50, c = idx - row * 50;
        *(uint4*)&As[row][c * 8] = *(const uint4*)(h1b + (size_t)(m0 + row) * 400 + c * 8);
    }
    if (t < 96) {
        int row = t / 3, c = t - row * 3;
        uint4 z = make_uint4(0u, 0u, 0u, 0u);
        *(uint4*)&As[row][400 + c * 8] = z;
    }
    __syncthreads();

    const int wave = t >> 6, lane = t & 63;
    const int lr = lane & 15, lg = lane >> 4;
    float s[2][4] = {};   // [m-tile][r] per-row partials (row = mt*16 + lg*4 + r)

    for (int nt = wave; nt < 25; nt += 4) {
        f32x4 acc0 = {}, acc1 = {};
        const unsigned short* bp = W2t + (size_t)(nt * 16 + lr) * 400 + lg * 8;
#pragma unroll
        for (int kt = 0; kt < 13; ++kt) {
            const int kk = kt * 32 + lg * 8;
            bf16x8 bw = {};
            if (kk < 400) bw = *(const bf16x8*)(bp + kt * 32);
            bf16x8 a0 = *(const bf16x8*)&As[lr][kk];
            bf16x8 a1 = *(const bf16x8*)&As[16 + lr][kk];
            acc0 = __builtin_amdgcn_mfma_f32_16x16x32_bf16(a0, bw, acc0, 0, 0, 0);
            acc1 = __builtin_amdgcn_mfma_f32_16x16x32_bf16(a1, bw, acc1, 0, 0, 0);
        }
        const int col = nt * 16 + lr;
        const float bb = b2[col], wo = wout[257 + col];
#pragma unroll
        for (int r = 0; r < 4; ++r) {
            s[0][r] = fmaf(fmaxf(acc0[r] + bb, 0.f), wo, s[0][r]);
            s[1][r] = fmaf(fmaxf(acc1[r] + bb, 0.f), wo, s[1][r]);
        }
    }
    // reduce across the 16 lr lanes (cols)
#pragma unroll
    for (int mt = 0; mt < 2; ++mt)
#pragma unroll
        for (int r = 0; r < 4; ++r) {
            float v = s[mt][r];
            v += __shfl_xor(v, 1, 64);
            v += __shfl_xor(v, 2, 64);
            v += __shfl_xor(v, 4, 64);
            v += __shfl_xor(v, 8, 64);
            if (lr == 0) red[wave][mt * 16 + lg * 4 + r] = v;
        }
    __syncthreads();
    if (t < 32) {
        const int b = m0 + t;
        float tot = red[0][t] + red[1][t] + red[2][t] + red[3][t]
                  + fdot0[b] + bout[0];
#pragma unroll
        for (int q = 0; q < 13; ++q)
            tot = fmaf(dense[(size_t)b * 13 + q], wout[657 + q], tot);
        out[b] = 1.f / (1.f + expf(-tot));
    }
}

extern "C" void kernel_launch(void* const* d_in, const int* in_sizes, int n_in,
                              void* d_out, int out_size, void* d_ws, size_t ws_size,
                              hipStream_t stream) {
    const float* dense  = (const float*)d_in[0];
    const int*   sparse = (const int*)  d_in[1];
    const float* E      = (const float*)d_in[2];
    const float* W0     = (const float*)d_in[3];
    const float* Wc1    = (const float*)d_in[4];
    const float* W1     = (const float*)d_in[5];
    const float* b1     = (const float*)d_in[6];
    const float* W2     = (const float*)d_in[7];
    const float* b2     = (const float*)d_in[8];
    const float* wlin   = (const float*)d_in[9];
    const float* blin   = (const float*)d_in[10];
    const float* wout   = (const float*)d_in[11];
    const float* bout   = (const float*)d_in[12];
    float* out = (float*)d_out;

    char* ws = (char*)d_ws;
    unsigned short* vb    = (unsigned short*)(ws + OFF_VB);
    float*          fdot0 = (float*)(ws + OFF_FD0);
    unsigned short* h1b   = (unsigned short*)(ws + OFF_H1B);
    unsigned short* W1t   = (unsigned short*)(ws + OFF_W1T);
    unsigned short* W2t   = (unsigned short*)(ws + OFF_W2T);
    unsigned short* K2T   = (unsigned short*)(ws + OFF_K2T);

    k0_all<<<338 + 169 + 32, 256, 0, stream>>>(W1, W2, W0, Wc1, wout, W1t, W2t, K2T);
    k1_embed_cin<<<B_, 256, 0, stream>>>(sparse, E, K2T, wlin, blin, wout, vb, fdot0);
    k2_h1<<<dim3(4, 128), 256, 0, stream>>>(vb, W1t, b1, h1b);
    k2_h2f<<<256, 256, 0, stream>>>(h1b, W2t, b2, wout, fdot0, dense, bout, out);
}

// Round 3
// 506.549 us; speedup vs baseline: 1.0087x; 1.0087x over previous
//
#include <hip/hip_runtime.h>
#include <hip/hip_bf16.h>
#include <math.h>

typedef __attribute__((ext_vector_type(8))) short bf16x8;
typedef __attribute__((ext_vector_type(4))) float f32x4;

#define B_ 8192
#define F_ 26
#define D_ 32
#define V_ 100000

// ---- ws layout (bytes), 16B-aligned ----
static const size_t OFF_VB   = 0;                    // bf16 8192x832 = 13631488
static const size_t OFF_FD0  = 13631488;             // f32 8192      = 32768
static const size_t OFF_W1T  = 13664256;             // bf16 512x832  = 851968 (rows 400..511 zero)
static const size_t OFF_W2T  = 14516224;             // bf16 512x512  = 524288 (row/col pads zero)
static const size_t OFF_K2T  = 15040512;             // bf16 2x352x32 = 45056  (hi plane, lo plane)
static const size_t OFF_B2P  = 15085568;             // f32 512 (b2 zero-padded)
static const size_t OFF_WO2P = 15087616;             // f32 512 (wout[257..656] zero-padded)
// total ~15.1 MB

// RNE bf16 (weights, one-time)
static __device__ __forceinline__ unsigned short f2b(float f) {
    unsigned int u = __float_as_uint(f);
    return (unsigned short)((u + 0x7FFF + ((u >> 16) & 1)) >> 16);
}
// truncating bf16 (activations)
static __device__ __forceinline__ unsigned short f2bt(float f) {
    return (unsigned short)(__float_as_uint(f) >> 16);
}
// pack two truncated bf16 in one v_perm_b32
static __device__ __forceinline__ unsigned int pk2t(float a, float b) {
    return __builtin_amdgcn_perm(__float_as_uint(b), __float_as_uint(a), 0x07060302u);
}
static __device__ __forceinline__ float bf2f(unsigned short u) {
    return __uint_as_float(((unsigned int)u) << 16);
}

// ======== K0: padded W1/W2 transposes + K2T + padded b2/wout2 ========
static __device__ __forceinline__ void transpose_pad(
    const float* __restrict__ src, unsigned short* __restrict__ dst,
    int K, int N, int Kpad, int Npad, int bx, int by)
{
    __shared__ float tl[32][33];
    const int lx = threadIdx.x & 31, ly = threadIdx.x >> 5;
    const int n0 = bx * 32, k0 = by * 32;
#pragma unroll
    for (int i = 0; i < 4; ++i) {
        int k = k0 + ly + i * 8, n = n0 + lx;
        tl[ly + i * 8][lx] = (k < K && n < N) ? src[(size_t)k * N + n] : 0.f;
    }
    __syncthreads();
#pragma unroll
    for (int i = 0; i < 4; ++i) {
        int n = n0 + ly + i * 8, k = k0 + lx;
        if (n < Npad && k < Kpad) dst[(size_t)n * Kpad + k] = f2b(tl[lx][ly + i * 8]);
    }
}

__global__ __launch_bounds__(256) void k0_all(
    const float* __restrict__ W1, const float* __restrict__ W2,
    const float* __restrict__ W0, const float* __restrict__ Wc1,
    const float* __restrict__ wout, const float* __restrict__ b2,
    unsigned short* __restrict__ W1t, unsigned short* __restrict__ W2t,
    unsigned short* __restrict__ K2T,
    float* __restrict__ b2p, float* __restrict__ wo2p)
{
    __shared__ float Mi[128];
    int bid = blockIdx.x;
    const int t = threadIdx.x;
    if (bid < 416) { transpose_pad(W1, W1t, 832, 400, 832, 512, bid % 16, bid / 16); return; }
    bid -= 416;
    if (bid < 256) { transpose_pad(W2, W2t, 400, 400, 512, 512, bid % 16, bid / 16); return; }
    bid -= 256;
    if (bid < 32) {
        // K2 block: fixed i = bid. Mi[j] = sum_h Wc1[i][j][h]*wout2[h] (i<26),
        // i==26 -> wout1[j], i>26 -> 0. Then K2T[q][i] = sum_j W0sym[q,j]*Mi[j], hi/lo bf16.
        const int i = bid;
        if (t < 128) {
            float m = 0.f;
            if (i < F_) {
                const float* row = Wc1 + ((size_t)i * 128 + t) * 128;
                for (int h = 0; h < 128; h += 4) {
                    float4 a = *(const float4*)(row + h);
                    m = fmaf(a.x, wout[129 + h],     m);
                    m = fmaf(a.y, wout[129 + h + 1], m);
                    m = fmaf(a.z, wout[129 + h + 2], m);
                    m = fmaf(a.w, wout[129 + h + 3], m);
                }
            } else if (i == F_) {
                m = wout[1 + t];
            }
            Mi[t] = m;
        }
        __syncthreads();
        for (int q = t; q < 352; q += 256) {
            float s = 0.f;
            if (q < 351 && i <= F_) {
                int a = 0, base = 0;
                while (base + (F_ - a) <= q) { base += F_ - a; ++a; }
                int b = a + (q - base);
                const float* r0 = W0 + ((size_t)a * F_ + b) * 128;
                const float* r1 = W0 + ((size_t)b * F_ + a) * 128;
                if (a == b) {
                    for (int j = 0; j < 128; j += 4) {
                        float4 w = *(const float4*)(r0 + j);
                        s += w.x * Mi[j] + w.y * Mi[j + 1] + w.z * Mi[j + 2] + w.w * Mi[j + 3];
                    }
                } else {
                    for (int j = 0; j < 128; j += 4) {
                        float4 w  = *(const float4*)(r0 + j);
                        float4 w1 = *(const float4*)(r1 + j);
                        s += (w.x + w1.x) * Mi[j]     + (w.y + w1.y) * Mi[j + 1]
                           + (w.z + w1.z) * Mi[j + 2] + (w.w + w1.w) * Mi[j + 3];
                    }
                }
            }
            unsigned short hi = f2b(s);
            float lo = s - bf2f(hi);
            K2T[q * 32 + i] = hi;                 // hi plane [352][32]
            K2T[11264 + q * 32 + i] = f2b(lo);    // lo plane
        }
        return;
    }
    // pad vectors
    for (int c = t; c < 512; c += 256) {
        b2p[c]  = (c < 400) ? b2[c] : 0.f;
        wo2p[c] = (c < 400) ? wout[257 + c] : 0.f;
    }
}

// ======== K1: one b per block: gather + Ht MFMA + in-register pe dot ========
__global__ __launch_bounds__(256) void k1_embed_cin(
    const int*   __restrict__ sparse,
    const float* __restrict__ E,
    const unsigned short* __restrict__ K2T,
    const float* __restrict__ wlin,
    const float* __restrict__ blin,
    const float* __restrict__ wout,
    unsigned short* __restrict__ vb,
    float* __restrict__ fdot0)
{
    __shared__ __align__(16) unsigned short embT[32][40];  // [d][i]; col26=1.0, 27..31=0
    __shared__ unsigned int PQ[352];                        // i | (j<<16)
    __shared__ int idxs[F_];
    __shared__ float red[4];

    const int b = blockIdx.x, t = threadIdx.x;
    float cind = 0.f;

    if (t < F_) {
        int id = sparse[b * F_ + t];
        idxs[t] = id;
        cind = (float)id * wlin[t] * wout[0];          // lin folded into the block dot
        int base = F_ * t - (t * (t - 1)) / 2;
        for (int j = t; j < F_; ++j)
            PQ[base + j - t] = (unsigned)t | ((unsigned)j << 16);
    }
    if (t == F_) PQ[351] = 0u;                          // pad row (K2T row 351 is zero)
    if (t >= 32 && t < 64) {                            // ones col + zero pad cols
        int d = t - 32;
        embT[d][26] = 0x3F80;                           // bf16 1.0
        embT[d][27] = 0; embT[d][28] = 0; embT[d][29] = 0;
        embT[d][30] = 0; embT[d][31] = 0;
    }
    __syncthreads();

    // gather 26 rows x 8 float4 -> vb (global, bf16) + embT (transposed LDS)
    if (t < 208) {
        int f = t >> 3, q = t & 7;
        float4 v4 = *(const float4*)(E + ((size_t)f * V_ + idxs[f]) * D_ + q * 4);
        uint2 uu; uu.x = pk2t(v4.x, v4.y); uu.y = pk2t(v4.z, v4.w);
        *(uint2*)(vb + (size_t)b * 832 + f * 32 + q * 4) = uu;
        embT[q * 4 + 0][f] = f2bt(v4.x);
        embT[q * 4 + 1][f] = f2bt(v4.y);
        embT[q * 4 + 2][f] = f2bt(v4.z);
        embT[q * 4 + 3][f] = f2bt(v4.w);
    }
    __syncthreads();

    // Ht[d][q] = sum_i embT[d][i]*K2[q][i] via MFMA; dot vs pe[q,d]=emb_i[d]*emb_j[d]
    const int wave = t >> 6, lane = t & 63;
    const int lr = lane & 15, lg = lane >> 4;
    const int mt = wave & 1;            // m-tile (d-half) fixed per wave
    const int nb = wave >> 1;           // nt = 2*s + nb
    bf16x8 af = *(const bf16x8*)&embT[mt * 16 + lr][lg * 8];
    const unsigned short* ebase = &embT[mt * 16 + lg * 4][0];
    const unsigned short* Kb = K2T + (size_t)lr * 32 + lg * 8;

#pragma unroll
    for (int s = 0; s < 11; ++s) {
        const int nt = 2 * s + nb;
        bf16x8 bh = *(const bf16x8*)(Kb + (size_t)nt * 512);
        bf16x8 bl = *(const bf16x8*)(Kb + 11264 + (size_t)nt * 512);
        f32x4 h = {};
        h = __builtin_amdgcn_mfma_f32_16x16x32_bf16(af, bl, h, 0, 0, 0);
        h = __builtin_amdgcn_mfma_f32_16x16x32_bf16(af, bh, h, 0, 0, 0);
        unsigned pq = PQ[nt * 16 + lr];
        int oi = (int)(pq & 0xFFFFu), oj = (int)(pq >> 16);
#pragma unroll
        for (int r = 0; r < 4; ++r) {
            float ei = bf2f(ebase[r * 40 + oi]);
            float ej = bf2f(ebase[r * 40 + oj]);
            cind = fmaf(ei * ej, h[r], cind);
        }
    }

#pragma unroll
    for (int off = 1; off <= 32; off <<= 1) cind += __shfl_xor(cind, off, 64);
    if (lane == 0) red[wave] = cind;
    __syncthreads();
    if (t == 0) fdot0[b] = red[0] + red[1] + red[2] + red[3] + blin[0] * wout[0];
}

// ======== K23: fused MLP tail. 256 blocks x 512 thr; 32 rows/block; h1 in LDS only ========
__global__ __launch_bounds__(512) void k23_mlp(
    const unsigned short* __restrict__ vb,
    const unsigned short* __restrict__ W1t,   // [512][832], rows 400.. zero
    const unsigned short* __restrict__ W2t,   // [512][512], pads zero
    const float* __restrict__ b1,
    const float* __restrict__ b2p,            // [512]
    const float* __restrict__ wo2p,           // [512]
    const float* __restrict__ fdot0,
    const float* __restrict__ dense,
    const float* __restrict__ wout,
    const float* __restrict__ bout,
    float* __restrict__ out)
{
    __shared__ __align__(16) unsigned short As1[32][840];  // vb strip (stride pad for banking)
    __shared__ __align__(16) unsigned short h1s[32][520];  // h1 strip, cols 0..511
    __shared__ float red[8][32];

    const int t = threadIdx.x;
    const int m0 = blockIdx.x * 32;

    // P1: stage 32x832 bf16 rows of vb
    {
        const int row = t >> 4, c0 = t & 15;
        const unsigned short* src = vb + (size_t)(m0 + row) * 832;
#pragma unroll
        for (int j = 0; j < 7; ++j) {
            int c = c0 + j * 16;
            if (c < 104) *(uint4*)&As1[row][c * 8] = *(const uint4*)(src + c * 8);
        }
    }
    __syncthreads();

    const int wave = t >> 6, lane = t & 63;
    const int lr = lane & 15, lg = lane >> 4;

    // GEMM1: h1 strip = relu(As1 @ W1t^T + b1); 32 nt tiles, 4 per wave, guard-free
    {
        f32x4 acc[4][2] = {};
        const unsigned short* bp0 = W1t + (size_t)((wave +  0) * 16 + lr) * 832 + lg * 8;
        const unsigned short* bp1 = W1t + (size_t)((wave +  8) * 16 + lr) * 832 + lg * 8;
        const unsigned short* bp2 = W1t + (size_t)((wave + 16) * 16 + lr) * 832 + lg * 8;
        const unsigned short* bp3 = W1t + (size_t)((wave + 24) * 16 + lr) * 832 + lg * 8;
#pragma unroll 2
        for (int kt = 0; kt < 26; ++kt) {
            const int kk = kt * 32 + lg * 8;
            bf16x8 a0 = *(const bf16x8*)&As1[lr][kk];
            bf16x8 a1 = *(const bf16x8*)&As1[16 + lr][kk];
            bf16x8 b0 = *(const bf16x8*)(bp0 + kt * 32);
            bf16x8 b1w = *(const bf16x8*)(bp1 + kt * 32);
            bf16x8 b2w = *(const bf16x8*)(bp2 + kt * 32);
            bf16x8 b3w = *(const bf16x8*)(bp3 + kt * 32);
            acc[0][0] = __builtin_amdgcn_mfma_f32_16x16x32_bf16(a0, b0,  acc[0][0], 0, 0, 0);
            acc[0][1] = __builtin_amdgcn_mfma_f32_16x16x32_bf16(a1, b0,  acc[0][1], 0, 0, 0);
            acc[1][0] = __builtin_amdgcn_mfma_f32_16x16x32_bf16(a0, b1w, acc[1][0], 0, 0, 0);
            acc[1][1] = __builtin_amdgcn_mfma_f32_16x16x32_bf16(a1, b1w, acc[1][1], 0, 0, 0);
            acc[2][0] = __builtin_amdgcn_mfma_f32_16x16x32_bf16(a0, b2w, acc[2][0], 0, 0, 0);
            acc[2][1] = __builtin_amdgcn_mfma_f32_16x16x32_bf16(a1, b2w, acc[2][1], 0, 0, 0);
            acc[3][0] = __builtin_amdgcn_mfma_f32_16x16x32_bf16(a0, b3w, acc[3][0], 0, 0, 0);
            acc[3][1] = __builtin_amdgcn_mfma_f32_16x16x32_bf16(a1, b3w, acc[3][1], 0, 0, 0);
        }
        // epilogue: bias+relu -> h1s (zero for padded cols)
#pragma unroll
        for (int q = 0; q < 4; ++q) {
            const int col = (wave + 8 * q) * 16 + lr;
            const bool vld = col < 400;
            const float bb = vld ? b1[col] : 0.f;
#pragma unroll
            for (int r = 0; r < 4; ++r) {
                float v0 = fmaxf(acc[q][0][r] + bb, 0.f);
                float v1 = fmaxf(acc[q][1][r] + bb, 0.f);
                h1s[lg * 4 + r][col]      = vld ? f2bt(v0) : (unsigned short)0;
                h1s[16 + lg * 4 + r][col] = vld ? f2bt(v1) : (unsigned short)0;
            }
        }
    }
    __syncthreads();

    // GEMM2 + fold: s += relu(h1s @ W2t^T + b2) . wout2
    {
        f32x4 acc[4][2] = {};
        const unsigned short* bp0 = W2t + (size_t)((wave +  0) * 16 + lr) * 512 + lg * 8;
        const unsigned short* bp1 = W2t + (size_t)((wave +  8) * 16 + lr) * 512 + lg * 8;
        const unsigned short* bp2 = W2t + (size_t)((wave + 16) * 16 + lr) * 512 + lg * 8;
        const unsigned short* bp3 = W2t + (size_t)((wave + 24) * 16 + lr) * 512 + lg * 8;
#pragma unroll 2
        for (int kt = 0; kt < 16; ++kt) {
            const int kk = kt * 32 + lg * 8;
            bf16x8 a0 = *(const bf16x8*)&h1s[lr][kk];
            bf16x8 a1 = *(const bf16x8*)&h1s[16 + lr][kk];
            bf16x8 b0 = *(const bf16x8*)(bp0 + kt * 32);
            bf16x8 b1w = *(const bf16x8*)(bp1 + kt * 32);
            bf16x8 b2w = *(const bf16x8*)(bp2 + kt * 32);
            bf16x8 b3w = *(const bf16x8*)(bp3 + kt * 32);
            acc[0][0] = __builtin_amdgcn_mfma_f32_16x16x32_bf16(a0, b0,  acc[0][0], 0, 0, 0);
            acc[0][1] = __builtin_amdgcn_mfma_f32_16x16x32_bf16(a1, b0,  acc[0][1], 0, 0, 0);
            acc[1][0] = __builtin_amdgcn_mfma_f32_16x16x32_bf16(a0, b1w, acc[1][0], 0, 0, 0);
            acc[1][1] = __builtin_amdgcn_mfma_f32_16x16x32_bf16(a1, b1w, acc[1][1], 0, 0, 0);
            acc[2][0] = __builtin_amdgcn_mfma_f32_16x16x32_bf16(a0, b2w, acc[2][0], 0, 0, 0);
            acc[2][1] = __builtin_amdgcn_mfma_f32_16x16x32_bf16(a1, b2w, acc[2][1], 0, 0, 0);
            acc[3][0] = __builtin_amdgcn_mfma_f32_16x16x32_bf16(a0, b3w, acc[3][0], 0, 0, 0);
            acc[3][1] = __builtin_amdgcn_mfma_f32_16x16x32_bf16(a1, b3w, acc[3][1], 0, 0, 0);
        }
        float s0[4] = {0.f, 0.f, 0.f, 0.f}, s1[4] = {0.f, 0.f, 0.f, 0.f};
#pragma unroll
        for (int q = 0; q < 4; ++q) {
            const int col = (wave + 8 * q) * 16 + lr;
            const float bb = b2p[col], wo = wo2p[col];
#pragma unroll
            for (int r = 0; r < 4; ++r) {
                s0[r] = fmaf(fmaxf(acc[q][0][r] + bb, 0.f), wo, s0[r]);
                s1[r] = fmaf(fmaxf(acc[q][1][r] + bb, 0.f), wo, s1[r]);
            }
        }
#pragma unroll
        for (int r = 0; r < 4; ++r) {
            float v0 = s0[r], v1 = s1[r];
            v0 += __shfl_xor(v0, 1, 64); v1 += __shfl_xor(v1, 1, 64);
            v0 += __shfl_xor(v0, 2, 64); v1 += __shfl_xor(v1, 2, 64);
            v0 += __shfl_xor(v0, 4, 64); v1 += __shfl_xor(v1, 4, 64);
            v0 += __shfl_xor(v0, 8, 64); v1 += __shfl_xor(v1, 8, 64);
            if (lr == 0) {
                red[wave][lg * 4 + r] = v0;
                red[wave][16 + lg * 4 + r] = v1;
            }
        }
    }
    __syncthreads();

    if (t < 32) {
        const int b = m0 + t;
        float tot = fdot0[b] + bout[0];
#pragma unroll
        for (int w = 0; w < 8; ++w) tot += red[w][t];
#pragma unroll
        for (int q = 0; q < 13; ++q)
            tot = fmaf(dense[(size_t)b * 13 + q], wout[657 + q], tot);
        out[b] = 1.f / (1.f + expf(-tot));
    }
}

extern "C" void kernel_launch(void* const* d_in, const int* in_sizes, int n_in,
                              void* d_out, int out_size, void* d_ws, size_t ws_size,
                              hipStream_t stream) {
    const float* dense  = (const float*)d_in[0];
    const int*   sparse = (const int*)  d_in[1];
    const float* E      = (const float*)d_in[2];
    const float* W0     = (const float*)d_in[3];
    const float* Wc1    = (const float*)d_in[4];
    const float* W1     = (const float*)d_in[5];
    const float* b1     = (const float*)d_in[6];
    const float* W2     = (const float*)d_in[7];
    const float* b2     = (const float*)d_in[8];
    const float* wlin   = (const float*)d_in[9];
    const float* blin   = (const float*)d_in[10];
    const float* wout   = (const float*)d_in[11];
    const float* bout   = (const float*)d_in[12];
    float* out = (float*)d_out;

    char* ws = (char*)d_ws;
    unsigned short* vb    = (unsigned short*)(ws + OFF_VB);
    float*          fdot0 = (float*)(ws + OFF_FD0);
    unsigned short* W1t   = (unsigned short*)(ws + OFF_W1T);
    unsigned short* W2t   = (unsigned short*)(ws + OFF_W2T);
    unsigned short* K2T   = (unsigned short*)(ws + OFF_K2T);
    float*          b2p   = (float*)(ws + OFF_B2P);
    float*          wo2p  = (float*)(ws + OFF_WO2P);

    k0_all<<<416 + 256 + 32 + 1, 256, 0, stream>>>(W1, W2, W0, Wc1, wout, b2,
                                                   W1t, W2t, K2T, b2p, wo2p);
    k1_embed_cin<<<B_, 256, 0, stream>>>(sparse, E, K2T, wlin, blin, wout, vb, fdot0);
    k23_mlp<<<256, 512, 0, stream>>>(vb, W1t, W2t, b1, b2p, wo2p,
                                     fdot0, dense, wout, bout, out);
}